// Round 13
// baseline (73.396 us; speedup 1.0000x reference)
//
#include <hip/hip_runtime.h>
#include <math.h>

#define NB 8192
#define ND 512
#define NPROTO 16
#define NBLK 256                   // k_norm grid
#define TINV 14.285714285714286f   // 1/0.07
#define PW_BLOCKS 256
#define PL_BLOCKS 256

typedef short short8 __attribute__((ext_vector_type(8)));
typedef float float4v __attribute__((ext_vector_type(4)));

__device__ __forceinline__ unsigned short f2bf(float f) {
  unsigned u = __builtin_bit_cast(unsigned, f);
  unsigned r = (u + 0x7FFFu + ((u >> 16) & 1u)) >> 16;
  return (unsigned short)r;
}
__device__ __forceinline__ float bflo(unsigned u) {
  return __builtin_bit_cast(float, u << 16);
}
__device__ __forceinline__ float bfhi(unsigned u) {
  return __builtin_bit_cast(float, u & 0xFFFF0000u);
}
// async 16B global->LDS (wave-uniform LDS base, per-lane global src)
__device__ __forceinline__ void gld16(const unsigned short* g, unsigned short* l) {
  __builtin_amdgcn_global_load_lds(
      (const __attribute__((address_space(1))) void*)g,
      (__attribute__((address_space(3))) void*)l, 16, 0, 0);
}

// ---- K1: wave-per-row normalize + bf16 store + non-atomic partial sums ----
__global__ __launch_bounds__(512) void k_norm(
    const float* __restrict__ z, const float* __restrict__ attr,
    unsigned short* __restrict__ znb, float* __restrict__ partialSum,
    int* __restrict__ code)
{
  __shared__ float acc[NPROTO * ND];   // 32 KB
  const int t = threadIdx.x, lane = t & 63, wid = t >> 6;
  for (int i = t; i < NPROTO * ND; i += 512) acc[i] = 0.f;
  __syncthreads();
  #pragma unroll
  for (int rr = 0; rr < 4; ++rr) {
    const int r = blockIdx.x * 32 + wid * 4 + rr;
    const float* zr = z + (size_t)r * ND;
    float v[8];
    #pragma unroll
    for (int jj = 0; jj < 8; ++jj) v[jj] = zr[lane + jj * 64];
    float s = 0.f;
    #pragma unroll
    for (int jj = 0; jj < 8; ++jj) s += v[jj] * v[jj];
    #pragma unroll
    for (int o = 32; o > 0; o >>= 1) s += __shfl_xor(s, o);
    const float inv = 1.f / fmaxf(sqrtf(s), 1e-12f);
    const float* a = attr + (size_t)r * 4;
    const int c = (a[0] > 0.5f ? 8 : 0) | (a[1] > 0.5f ? 4 : 0) |
                  (a[2] > 0.5f ? 2 : 0) | (a[3] > 0.5f ? 1 : 0);
    float* accRow = acc + c * ND;
    #pragma unroll
    for (int jj = 0; jj < 8; ++jj) {
      const float zv = v[jj] * inv;
      atomicAdd(&accRow[lane + jj * 64], zv);        // LDS, consecutive banks
      znb[(size_t)r * ND + lane + jj * 64] = f2bf(zv);
    }
    if (lane == 0) code[r] = c;
  }
  __syncthreads();
  for (int i = t; i < NPROTO * ND; i += 512) {      // full overwrite: no pre-zero
    const int p = i >> 9, d = i & 511;
    partialSum[(size_t)((p << 8) | blockIdx.x) * ND + d] = acc[i];
  }
}

// ---- K1b: stage-1 reduce: 256 blocks, (p,c) sums 16 partials --------------
__global__ __launch_bounds__(256) void k_reduce1(
    const float* __restrict__ partialSum, float* __restrict__ partial2)
{
  const int t = threadIdx.x;
  const int p = blockIdx.x >> 4, c = blockIdx.x & 15;
  const float* base = partialSum + (size_t)(p * NBLK + c * 16) * ND;
  float s0 = 0.f, s1 = 0.f;
  #pragma unroll
  for (int k = 0; k < 16; ++k) {
    s0 += base[k * ND + t];
    s1 += base[k * ND + t + 256];
  }
  partial2[(size_t)(p * 16 + c) * ND + t] = s0;
  partial2[(size_t)(p * 16 + c) * ND + t + 256] = s1;
}

// ---- K2: 16 blocks: final reduce + normalize + validList ------------------
__global__ __launch_bounds__(512) void k_protonorm(
    const float* __restrict__ partial2, const int* __restrict__ code,
    float* __restrict__ protos, int* __restrict__ validList,
    int* __restrict__ validCnt)
{
  __shared__ float red[8];
  __shared__ int lcnt;
  const int t = threadIdx.x, lane = t & 63, wid = t >> 6;
  const int p = blockIdx.x;
  if (t == 0) lcnt = 0;
  __syncthreads();
  const float* base = partial2 + (size_t)p * 16 * ND;
  float s = 0.f;
  #pragma unroll
  for (int c = 0; c < 16; ++c)
    s += base[c * ND + t];
  float cl = 0.f;
  for (int r = t; r < NB; r += 512) {
    const int match = (code[r] == p) ? 1 : 0;
    cl += (float)match;
    if (p == NPROTO - 1 && match) {
      const int slot = atomicAdd(&lcnt, 1);
      validList[slot] = r;
    }
  }
  #pragma unroll
  for (int o = 32; o > 0; o >>= 1) cl += __shfl_xor(cl, o);
  if (lane == 0) red[wid] = cl;
  __syncthreads();
  const float cTot = red[0]+red[1]+red[2]+red[3]+red[4]+red[5]+red[6]+red[7];
  __syncthreads();
  const float mean = s / fmaxf(cTot, 1.f);
  float sq = mean * mean;
  #pragma unroll
  for (int o = 32; o > 0; o >>= 1) sq += __shfl_xor(sq, o);
  if (lane == 0) red[wid] = sq;
  __syncthreads();
  const float sum = red[0]+red[1]+red[2]+red[3]+red[4]+red[5]+red[6]+red[7];
  const float scale = (cTot > 0.f) ? 1.f / fmaxf(sqrtf(sum), 1e-12f) : 0.f;
  protos[p * ND + t] = mean * scale;
  if (p == NPROTO - 1 && t == 0) validCnt[0] = lcnt;
}

// ---- K3: fused {pairwise GEMM: async dbuf staging | protoloss} ------------
// LDS: A0 8K | A1 8K | B0 32K | B1 32K = 80 KB (2 blocks/CU)
#define PLD (ND + 4)
#define SMEM_BYTES 81920
__global__ __launch_bounds__(512) void k_main(
    const unsigned short* __restrict__ znb, const float* __restrict__ protos,
    const int* __restrict__ code, const int* __restrict__ validList,
    const int* __restrict__ validCnt,
    float* __restrict__ partialAll, float* __restrict__ partialPos,
    float* __restrict__ plPart)
{
  __shared__ __align__(16) char smem[SMEM_BYTES];
  __shared__ float red3[8];
  const int t = threadIdx.x, lane = t & 63, wid = t >> 6;
  const int bi = blockIdx.x;
  if (bi < PW_BLOCKS) {
    // -------- pairwise: 8 waves (2i x 4j), tile 64i x 256j, K-chunk 64 ----
    char* const Abuf[2] = { smem, smem + 8192 };
    char* const Bbuf[2] = { smem + 16384, smem + 49152 };
    const int wv = wid >> 2, ww = wid & 3;
    const int m = validCnt[0];
    const int nIT = (m + 63) >> 6;
    const int items = nIT * 32;
    const int grp = lane >> 4, cl = lane & 15;
    // A-stage constants for this thread (chunk ci == t)
    const int iaA = t >> 3;
    const int kqA = (t & 7) ^ (iaA & 7);
    for (int wi = bi; wi < items; wi += PW_BLOCKS) {
      const int i0 = (wi >> 5) * 64;
      const int jt = wi & 31;
      const int jb = jt * 256;
      const int slotA = i0 + iaA;
      const int srowA = (slotA < m) ? validList[slotA] : 0;
      // ---- prologue: async stage kc=0 into buf 0 ----
      {
        gld16(znb + (size_t)srowA * ND + kqA * 8,
              (unsigned short*)(Abuf[0] + wid * 1024));
        #pragma unroll
        for (int h = 0; h < 4; ++h) {
          const int ci = h * 512 + t;
          const int j = ci >> 3;
          const int kq = (t & 7) ^ (j & 7);
          gld16(znb + (size_t)(jb + j) * ND + kq * 8,
                (unsigned short*)(Bbuf[0] + h * 8192 + wid * 1024));
        }
      }
      float4v acc[2][4];
      #pragma unroll
      for (int mi = 0; mi < 2; ++mi)
        #pragma unroll
        for (int nj = 0; nj < 4; ++nj) acc[mi][nj] = (float4v)(0.f);
      int cur = 0;
      #pragma unroll
      for (int kc = 0; kc < 8; ++kc) {
        __syncthreads();   // drains pending gld16 (buf[cur] ready); all waves done with buf[cur^1]
        if (kc < 7) {      // async prefetch next chunk into other buffer
          const int k0 = (kc + 1) * 64;
          gld16(znb + (size_t)srowA * ND + k0 + kqA * 8,
                (unsigned short*)(Abuf[cur ^ 1] + wid * 1024));
          #pragma unroll
          for (int h = 0; h < 4; ++h) {
            const int ci = h * 512 + t;
            const int j = ci >> 3;
            const int kq = (t & 7) ^ (j & 7);
            gld16(znb + (size_t)(jb + j) * ND + k0 + kq * 8,
                  (unsigned short*)(Bbuf[cur ^ 1] + h * 8192 + wid * 1024));
          }
        }
        const char* aC = Abuf[cur];
        const char* bC = Bbuf[cur];
        #pragma unroll
        for (int ks = 0; ks < 2; ++ks) {
          const int kb = ks * 64 + grp * 16;
          short8 af[2], bf[4];
          #pragma unroll
          for (int mi = 0; mi < 2; ++mi) {
            const int rw = wv * 32 + mi * 16 + cl;
            af[mi] = *(const short8*)(aC + rw * 128 + (kb ^ ((rw & 7) << 4)));
          }
          #pragma unroll
          for (int nj = 0; nj < 4; ++nj) {
            const int rw = ww * 64 + nj * 16 + cl;
            bf[nj] = *(const short8*)(bC + rw * 128 + (kb ^ ((rw & 7) << 4)));
          }
          #pragma unroll
          for (int mi = 0; mi < 2; ++mi)
            #pragma unroll
            for (int nj = 0; nj < 4; ++nj)
              acc[mi][nj] = __builtin_amdgcn_mfma_f32_16x16x32_bf16(af[mi], bf[nj], acc[mi][nj], 0, 0, 0);
        }
        cur ^= 1;
      }
      // epilogue: exp, diag+pos masks, row sums, direct partial writes
      #pragma unroll
      for (int mi = 0; mi < 2; ++mi) {
        float sA[4] = {0.f, 0.f, 0.f, 0.f}, sP[4] = {0.f, 0.f, 0.f, 0.f};
        int ri[4];
        #pragma unroll
        for (int q = 0; q < 4; ++q) {
          const int sl = i0 + wv * 32 + mi * 16 + grp * 4 + q;
          ri[q] = (sl < m) ? validList[sl] : -1;
        }
        #pragma unroll
        for (int nj = 0; nj < 4; ++nj) {
          const int jl = ww * 64 + nj * 16 + cl;
          const int jg = jb + jl;
          const float ao = (code[jg] == NPROTO - 1) ? 1.f : 0.f;
          #pragma unroll
          for (int q = 0; q < 4; ++q) {
            float e = __expf(acc[mi][nj][q] * TINV);
            e = (jg == ri[q]) ? 0.f : e;
            sA[q] += e;
            sP[q] += e * ao;
          }
        }
        #pragma unroll
        for (int q = 0; q < 4; ++q) {
          #pragma unroll
          for (int o = 1; o < 16; o <<= 1) {
            sA[q] += __shfl_xor(sA[q], o);
            sP[q] += __shfl_xor(sP[q], o);
          }
        }
        if (cl == 0) {
          const int slot0 = i0 + wv * 32 + mi * 16 + grp * 4;
          const int jt2 = jt * 4 + ww;                      // 0..127
          if (slot0 + 3 < m) {
            *(float4*)&partialAll[(size_t)jt2 * NB + slot0] =
                make_float4(sA[0], sA[1], sA[2], sA[3]);
            *(float4*)&partialPos[(size_t)jt2 * NB + slot0] =
                make_float4(sP[0], sP[1], sP[2], sP[3]);
          } else {
            #pragma unroll
            for (int q = 0; q < 4; ++q) {
              if (slot0 + q < m) {
                partialAll[(size_t)jt2 * NB + slot0 + q] = sA[q];
                partialPos[(size_t)jt2 * NB + slot0 + q] = sP[q];
              }
            }
          }
        }
      }
    }
  } else {
    // -------- protoloss: 256 blocks x 512 thr, 32 rows each ---------------
    float* pl = (float*)smem;                               // [16][PLD]
    const int pb = bi - PW_BLOCKS;
    for (int i = t; i < NPROTO * ND; i += 512)
      pl[(i >> 9) * PLD + (i & 511)] = protos[i];
    __syncthreads();
    const int p = lane & 15, grp = lane >> 4;
    float lacc = 0.f;
    #pragma unroll
    for (int rr = 0; rr < 4; ++rr) {
      const int r = pb * 32 + wid * 4 + rr;
      const uint4* zr = (const uint4*)(znb + (size_t)r * ND + grp * 128);
      const float* pbp = &pl[p * PLD + grp * 128];
      float s = 0.f;
      #pragma unroll
      for (int it = 0; it < 16; ++it) {
        const uint4 u = zr[it];
        const float4 p0 = *(const float4*)(pbp + it * 8);
        const float4 p1 = *(const float4*)(pbp + it * 8 + 4);
        s += bflo(u.x)*p0.x + bfhi(u.x)*p0.y + bflo(u.y)*p0.z + bfhi(u.y)*p0.w;
        s += bflo(u.z)*p1.x + bfhi(u.z)*p1.y + bflo(u.w)*p1.z + bfhi(u.w)*p1.w;
      }
      s += __shfl_xor(s, 16);
      s += __shfl_xor(s, 32);
      const float e = __expf(s * TINV);
      float alls = e;
      alls += __shfl_xor(alls, 1);
      alls += __shfl_xor(alls, 2);
      alls += __shfl_xor(alls, 4);
      alls += __shfl_xor(alls, 8);
      const int c = code[r];
      const float pos = __shfl(e, (lane & ~15) | c);
      if (lane == 0) lacc += -logf(pos / fmaxf(alls, 1e-8f) + 1e-8f);
    }
    if (lane == 0) red3[wid] = lacc;
    __syncthreads();
    if (t == 0)
      plPart[pb] = red3[0]+red3[1]+red3[2]+red3[3]+red3[4]+red3[5]+red3[6]+red3[7];
  }
}

// ---- K4: finalize — 1024 thr, coalesced column reads, split-k halves ------
__global__ __launch_bounds__(1024) void k_final(
    const float* __restrict__ partialAll, const float* __restrict__ partialPos,
    const float* __restrict__ plPart, const int* __restrict__ validCnt,
    float* __restrict__ out)
{
  __shared__ float shA[1024], shP[1024];
  __shared__ float red[16], red2[16];
  const int t = threadIdx.x, lane = t & 63, wid = t >> 6;
  const int m = validCnt[0];
  const int nvalid = (m >= 2) ? m : 0;
  const int slot = t & 511, half = t >> 9;
  float sa = 0.f, sp = 0.f;
  if (slot < nvalid) {
    const int k0 = half * 64;
    #pragma unroll 8
    for (int k = k0; k < k0 + 64; ++k) {
      sa += partialAll[(size_t)k * NB + slot];   // coalesced across threads
      sp += partialPos[(size_t)k * NB + slot];
    }
  }
  shA[t] = sa; shP[t] = sp;
  __syncthreads();
  float s = 0.f;
  if (t < 512 && slot < nvalid) {
    const float A = shA[t] + shA[t + 512];
    const float P = shP[t] + shP[t + 512];
    s = -logf(P / (A + 1e-8f) + 1e-8f);
  }
  float pls = (t < PL_BLOCKS) ? plPart[t] : 0.f;
  #pragma unroll
  for (int o = 32; o > 0; o >>= 1) {
    s += __shfl_xor(s, o);
    pls += __shfl_xor(pls, o);
  }
  if (lane == 0) { red[wid] = s; red2[wid] = pls; }
  __syncthreads();
  if (t == 0) {
    float total = 0.f, plTot = 0.f;
    #pragma unroll
    for (int w = 0; w < 16; ++w) { total += red[w]; plTot += red2[w]; }
    const float proto = plTot / (float)NB;
    float loss = proto;
    if (nvalid > 0) loss = 0.7f * proto + 0.3f * (total / (float)nvalid);
    out[0] = loss;
  }
}

extern "C" void kernel_launch(void* const* d_in, const int* in_sizes, int n_in,
                              void* d_out, int out_size, void* d_ws, size_t ws_size,
                              hipStream_t stream) {
  const float* z = (const float*)d_in[0];
  const float* attr = (const float*)d_in[1];
  unsigned short* znb = (unsigned short*)d_ws;            // NB*ND bf16 (8 MB)
  float* partialSum = (float*)(znb + (size_t)NB * ND);    // [p][b][d] (8 MB)
  // overlay: partialSum is dead after k_reduce1/protonorm; k_main reuses it
  float* partialAll = partialSum;                         // [128][NB] (4 MB)
  float* partialPos = partialSum + (size_t)128 * NB;      // [128][NB] (4 MB)
  char* w = (char*)(partialSum + (size_t)NBLK * NPROTO * ND);
  float* partial2 = (float*)w;      w += (size_t)NPROTO * 16 * ND * 4;  // 512 KB
  int* validCnt = (int*)w;          w += 16;
  int* code = (int*)w;              w += NB * 4;
  int* validList = (int*)w;         w += NB * 4;
  float* protos = (float*)w;        w += NPROTO * ND * 4;
  float* plPart = (float*)w;        w += PL_BLOCKS * 4;
  k_norm<<<dim3(NBLK), dim3(512), 0, stream>>>(z, attr, znb, partialSum, code);
  k_reduce1<<<dim3(256), dim3(256), 0, stream>>>(partialSum, partial2);
  k_protonorm<<<dim3(NPROTO), dim3(512), 0, stream>>>(partial2, code, protos,
                                                      validList, validCnt);
  k_main<<<dim3(PW_BLOCKS + PL_BLOCKS), dim3(512), 0, stream>>>(
      znb, protos, code, validList, validCnt, partialAll, partialPos, plPart);
  k_final<<<dim3(1), dim3(1024), 0, stream>>>(partialAll, partialPos, plPart,
                                              validCnt, (float*)d_out);
}

// Round 14
// 72.052 us; speedup vs baseline: 1.0186x; 1.0186x over previous
//
#include <hip/hip_runtime.h>
#include <math.h>

#define NB 8192
#define ND 512
#define NPROTO 16
#define NBLK 256                   // k_norm grid
#define TINV 14.285714285714286f   // 1/0.07
#define PW_BLOCKS 256
#define PL_BLOCKS 256

typedef short short8 __attribute__((ext_vector_type(8)));
typedef float float4v __attribute__((ext_vector_type(4)));

__device__ __forceinline__ unsigned short f2bf(float f) {
  unsigned u = __builtin_bit_cast(unsigned, f);
  unsigned r = (u + 0x7FFFu + ((u >> 16) & 1u)) >> 16;
  return (unsigned short)r;
}
__device__ __forceinline__ float bflo(unsigned u) {
  return __builtin_bit_cast(float, u << 16);
}
__device__ __forceinline__ float bfhi(unsigned u) {
  return __builtin_bit_cast(float, u & 0xFFFF0000u);
}

// ---- K1: wave-per-row normalize + bf16 store + non-atomic partial sums ----
// block 0 also re-zeroes protoSumG (written only by the NEXT kernel: race-free)
__global__ __launch_bounds__(512) void k_norm(
    const float* __restrict__ z, const float* __restrict__ attr,
    unsigned short* __restrict__ znb, float* __restrict__ partialSum,
    int* __restrict__ code, float* __restrict__ protoSumG)
{
  __shared__ float acc[NPROTO * ND];   // 32 KB
  const int t = threadIdx.x, lane = t & 63, wid = t >> 6;
  for (int i = t; i < NPROTO * ND; i += 512) acc[i] = 0.f;
  if (blockIdx.x == 0)
    for (int i = t; i < NPROTO * ND; i += 512) protoSumG[i] = 0.f;
  __syncthreads();
  #pragma unroll
  for (int rr = 0; rr < 4; ++rr) {
    const int r = blockIdx.x * 32 + wid * 4 + rr;
    const float* zr = z + (size_t)r * ND;
    float v[8];
    #pragma unroll
    for (int jj = 0; jj < 8; ++jj) v[jj] = zr[lane + jj * 64];
    float s = 0.f;
    #pragma unroll
    for (int jj = 0; jj < 8; ++jj) s += v[jj] * v[jj];
    #pragma unroll
    for (int o = 32; o > 0; o >>= 1) s += __shfl_xor(s, o);
    const float inv = 1.f / fmaxf(sqrtf(s), 1e-12f);
    const float* a = attr + (size_t)r * 4;
    const int c = (a[0] > 0.5f ? 8 : 0) | (a[1] > 0.5f ? 4 : 0) |
                  (a[2] > 0.5f ? 2 : 0) | (a[3] > 0.5f ? 1 : 0);
    float* accRow = acc + c * ND;
    #pragma unroll
    for (int jj = 0; jj < 8; ++jj) {
      const float zv = v[jj] * inv;
      atomicAdd(&accRow[lane + jj * 64], zv);        // LDS, consecutive banks
      znb[(size_t)r * ND + lane + jj * 64] = f2bf(zv);
    }
    if (lane == 0) code[r] = c;
  }
  __syncthreads();
  for (int i = t; i < NPROTO * ND; i += 512) {      // full overwrite: no pre-zero
    const int p = i >> 9, d = i & 511;
    partialSum[(size_t)((p << 8) | blockIdx.x) * ND + d] = acc[i];
  }
}

// ---- K1b: 257 blocks: (p,c) sums 16 partials -> atomic finish into
//           protoSumG (16-way contention); block 256 builds validList -------
__global__ __launch_bounds__(256) void k_reduce1(
    const float* __restrict__ partialSum, const int* __restrict__ code,
    float* __restrict__ protoSumG, int* __restrict__ validList,
    int* __restrict__ validCnt)
{
  const int t = threadIdx.x;
  if (blockIdx.x < 256) {
    const int p = blockIdx.x >> 4, c = blockIdx.x & 15;
    const float* base = partialSum + (size_t)(p * NBLK + c * 16) * ND;
    float s0 = 0.f, s1 = 0.f;
    #pragma unroll
    for (int k = 0; k < 16; ++k) {
      s0 += base[k * ND + t];
      s1 += base[k * ND + t + 256];
    }
    atomicAdd(&protoSumG[p * ND + t], s0);
    atomicAdd(&protoSumG[p * ND + t + 256], s1);
  } else {
    __shared__ int lcnt;
    if (t == 0) lcnt = 0;
    __syncthreads();
    for (int r = t; r < NB; r += 256) {
      if (code[r] == NPROTO - 1) {
        const int s = atomicAdd(&lcnt, 1);
        validList[s] = r;
      }
    }
    __syncthreads();
    if (t == 0) validCnt[0] = lcnt;
  }
}

// ---- K3: fused {pairwise MFMA GEMM (R12-proven) | protoloss w/ in-block
//           proto normalization: sim = (z.S_p)/||S_p|| (c_p cancels)} -------
#define PLD (ND + 4)
#define SMEM_BYTES 41472
__global__ __launch_bounds__(512) void k_main(
    const unsigned short* __restrict__ znb, const float* __restrict__ protoSumG,
    const int* __restrict__ code, const int* __restrict__ validList,
    const int* __restrict__ validCnt,
    float* __restrict__ partialAll, float* __restrict__ partialPos,
    float* __restrict__ plPart)
{
  __shared__ __align__(16) char smem[SMEM_BYTES];
  __shared__ float red3[8];
  __shared__ float gSh[16];
  const int t = threadIdx.x, lane = t & 63, wid = t >> 6;
  const int bi = blockIdx.x;
  if (bi < PW_BLOCKS) {
    // -------- pairwise: 8 waves (2i x 4j), tile 64i x 256j, K-chunk 64 ----
    unsigned short* aT = (unsigned short*)smem;             // 64x64, 8 KB
    unsigned short* bT = aT + 64 * 64;                      // 256x64, 32 KB
    int* rowIdx = (int*)(bT + 256 * 64);                    // 64
    unsigned char* aoSh = (unsigned char*)(rowIdx + 64);    // 256
    const int wv = wid >> 2, ww = wid & 3;
    const int m = validCnt[0];
    const int nIT = (m + 63) >> 6;
    const int items = nIT * 32;                             // 32 j-tiles of 256
    const int grp = lane >> 4, cl = lane & 15;
    for (int wi = bi; wi < items; wi += PW_BLOCKS) {
      const int i0 = (wi >> 5) * 64;
      const int jt = wi & 31;
      const int jb = jt * 256;
      __syncthreads();
      if (t < 64) rowIdx[t] = (i0 + t < m) ? validList[i0 + t] : -1;
      if (t < 256) aoSh[t] = (code[jb + t] == NPROTO - 1) ? 1 : 0;
      float4v acc[2][4];
      #pragma unroll
      for (int mi = 0; mi < 2; ++mi)
        #pragma unroll
        for (int nj = 0; nj < 4; ++nj) acc[mi][nj] = (float4v)(0.f);
      for (int kc = 0; kc < 8; ++kc) {
        const int k0 = kc * 64;
        __syncthreads();
        {  // stage A: 64 rows x 8 chunks = 512, 1/thread
          const int ia = t >> 3, kq = t & 7;
          const int ri = rowIdx[ia];
          const int srow = (ri < 0) ? 0 : ri;
          const uint4 v = *(const uint4*)(znb + (size_t)srow * ND + k0 + kq * 8);
          *(uint4*)((char*)aT + ia * 128 + ((kq * 16) ^ ((ia & 7) << 4))) = v;
        }
        #pragma unroll
        for (int h = 0; h < 4; ++h) {  // stage B: 256 rows x 8 chunks, 4/thread
          const int f = t + h * 512;
          const int j = f >> 3, kq = f & 7;
          const uint4 v = *(const uint4*)(znb + (size_t)(jb + j) * ND + k0 + kq * 8);
          *(uint4*)((char*)bT + j * 128 + ((kq * 16) ^ ((j & 7) << 4))) = v;
        }
        __syncthreads();
        #pragma unroll
        for (int ks = 0; ks < 2; ++ks) {
          const int kb = ks * 64 + grp * 16;
          short8 af[2], bf[4];
          #pragma unroll
          for (int mi = 0; mi < 2; ++mi) {
            const int rw = wv * 32 + mi * 16 + cl;
            af[mi] = *(const short8*)((char*)aT + rw * 128 + (kb ^ ((rw & 7) << 4)));
          }
          #pragma unroll
          for (int nj = 0; nj < 4; ++nj) {
            const int rw = ww * 64 + nj * 16 + cl;
            bf[nj] = *(const short8*)((char*)bT + rw * 128 + (kb ^ ((rw & 7) << 4)));
          }
          #pragma unroll
          for (int mi = 0; mi < 2; ++mi)
            #pragma unroll
            for (int nj = 0; nj < 4; ++nj)
              acc[mi][nj] = __builtin_amdgcn_mfma_f32_16x16x32_bf16(af[mi], bf[nj], acc[mi][nj], 0, 0, 0);
        }
      }
      // epilogue: exp, diag+pos masks, row sums, direct partial writes
      #pragma unroll
      for (int mi = 0; mi < 2; ++mi) {
        float sA[4] = {0.f, 0.f, 0.f, 0.f}, sP[4] = {0.f, 0.f, 0.f, 0.f};
        int ri[4];
        #pragma unroll
        for (int q = 0; q < 4; ++q) ri[q] = rowIdx[wv * 32 + mi * 16 + grp * 4 + q];
        #pragma unroll
        for (int nj = 0; nj < 4; ++nj) {
          const int jl = ww * 64 + nj * 16 + cl;
          const int jg = jb + jl;
          const float ao = aoSh[jl] ? 1.f : 0.f;
          #pragma unroll
          for (int q = 0; q < 4; ++q) {
            float e = __expf(acc[mi][nj][q] * TINV);
            e = (jg == ri[q]) ? 0.f : e;
            sA[q] += e;
            sP[q] += e * ao;
          }
        }
        #pragma unroll
        for (int q = 0; q < 4; ++q) {
          #pragma unroll
          for (int o = 1; o < 16; o <<= 1) {
            sA[q] += __shfl_xor(sA[q], o);
            sP[q] += __shfl_xor(sP[q], o);
          }
        }
        if (cl == 0) {
          const int slot0 = i0 + wv * 32 + mi * 16 + grp * 4;
          const int jt2 = jt * 4 + ww;                      // 0..127
          if (slot0 + 3 < m) {
            *(float4*)&partialAll[(size_t)jt2 * NB + slot0] =
                make_float4(sA[0], sA[1], sA[2], sA[3]);
            *(float4*)&partialPos[(size_t)jt2 * NB + slot0] =
                make_float4(sP[0], sP[1], sP[2], sP[3]);
          } else {
            #pragma unroll
            for (int q = 0; q < 4; ++q) {
              if (slot0 + q < m) {
                partialAll[(size_t)jt2 * NB + slot0 + q] = sA[q];
                partialPos[(size_t)jt2 * NB + slot0 + q] = sP[q];
              }
            }
          }
        }
      }
    }
  } else {
    // -------- protoloss: in-block normalize of raw segment sums -----------
    float* pl = (float*)smem;                               // [16][PLD]
    const int pb = bi - PW_BLOCKS;
    for (int i = t; i < NPROTO * ND; i += 512)
      pl[(i >> 9) * PLD + (i & 511)] = protoSumG[i];
    __syncthreads();
    {  // g_p = 1/||S_p||  (32 threads per proto)
      const int p = t >> 5, l32 = t & 31;
      float sq = 0.f;
      #pragma unroll
      for (int k = 0; k < 16; ++k) {
        const float v = pl[p * PLD + l32 + k * 32];
        sq += v * v;
      }
      #pragma unroll
      for (int o = 1; o < 32; o <<= 1) sq += __shfl_xor(sq, o);
      if (l32 == 0) gSh[p] = 1.f / fmaxf(sqrtf(sq), 1e-12f);
    }
    __syncthreads();
    for (int i = t; i < NPROTO * ND; i += 512)
      pl[(i >> 9) * PLD + (i & 511)] *= gSh[i >> 9];
    __syncthreads();
    const int p = lane & 15, grp = lane >> 4;
    float lacc = 0.f;
    #pragma unroll
    for (int rr = 0; rr < 4; ++rr) {
      const int r = pb * 32 + wid * 4 + rr;
      const uint4* zr = (const uint4*)(znb + (size_t)r * ND + grp * 128);
      const float* pbp = &pl[p * PLD + grp * 128];
      float s = 0.f;
      #pragma unroll
      for (int it = 0; it < 16; ++it) {
        const uint4 u = zr[it];
        const float4 p0 = *(const float4*)(pbp + it * 8);
        const float4 p1 = *(const float4*)(pbp + it * 8 + 4);
        s += bflo(u.x)*p0.x + bfhi(u.x)*p0.y + bflo(u.y)*p0.z + bfhi(u.y)*p0.w;
        s += bflo(u.z)*p1.x + bfhi(u.z)*p1.y + bflo(u.w)*p1.z + bfhi(u.w)*p1.w;
      }
      s += __shfl_xor(s, 16);
      s += __shfl_xor(s, 32);
      const float e = __expf(s * TINV);
      float alls = e;
      alls += __shfl_xor(alls, 1);
      alls += __shfl_xor(alls, 2);
      alls += __shfl_xor(alls, 4);
      alls += __shfl_xor(alls, 8);
      const int c = code[r];
      const float pos = __shfl(e, (lane & ~15) | c);
      if (lane == 0) lacc += -logf(pos / fmaxf(alls, 1e-8f) + 1e-8f);
    }
    if (lane == 0) red3[wid] = lacc;
    __syncthreads();
    if (t == 0)
      plPart[pb] = red3[0]+red3[1]+red3[2]+red3[3]+red3[4]+red3[5]+red3[6]+red3[7];
  }
}

// ---- K4: finalize — 1024 thr, coalesced column reads, split-k halves ------
__global__ __launch_bounds__(1024) void k_final(
    const float* __restrict__ partialAll, const float* __restrict__ partialPos,
    const float* __restrict__ plPart, const int* __restrict__ validCnt,
    float* __restrict__ out)
{
  __shared__ float shA[1024], shP[1024];
  __shared__ float red[16], red2[16];
  const int t = threadIdx.x, lane = t & 63, wid = t >> 6;
  const int m = validCnt[0];
  const int nvalid = (m >= 2) ? m : 0;
  const int slot = t & 511, half = t >> 9;
  float sa = 0.f, sp = 0.f;
  if (slot < nvalid) {
    const int k0 = half * 64;
    #pragma unroll 8
    for (int k = k0; k < k0 + 64; ++k) {
      sa += partialAll[(size_t)k * NB + slot];   // coalesced across threads
      sp += partialPos[(size_t)k * NB + slot];
    }
  }
  shA[t] = sa; shP[t] = sp;
  __syncthreads();
  float s = 0.f;
  if (t < 512 && slot < nvalid) {
    const float A = shA[t] + shA[t + 512];
    const float P = shP[t] + shP[t + 512];
    s = -logf(P / (A + 1e-8f) + 1e-8f);
  }
  float pls = (t < PL_BLOCKS) ? plPart[t] : 0.f;
  #pragma unroll
  for (int o = 32; o > 0; o >>= 1) {
    s += __shfl_xor(s, o);
    pls += __shfl_xor(pls, o);
  }
  if (lane == 0) { red[wid] = s; red2[wid] = pls; }
  __syncthreads();
  if (t == 0) {
    float total = 0.f, plTot = 0.f;
    #pragma unroll
    for (int w = 0; w < 16; ++w) { total += red[w]; plTot += red2[w]; }
    const float proto = plTot / (float)NB;
    float loss = proto;
    if (nvalid > 0) loss = 0.7f * proto + 0.3f * (total / (float)nvalid);
    out[0] = loss;
  }
}

extern "C" void kernel_launch(void* const* d_in, const int* in_sizes, int n_in,
                              void* d_out, int out_size, void* d_ws, size_t ws_size,
                              hipStream_t stream) {
  const float* z = (const float*)d_in[0];
  const float* attr = (const float*)d_in[1];
  unsigned short* znb = (unsigned short*)d_ws;            // NB*ND bf16 (8 MB)
  float* partialSum = (float*)(znb + (size_t)NB * ND);    // [p][b][d] (8 MB)
  // overlay: partialSum is dead after k_reduce1; k_main reuses it
  float* partialAll = partialSum;                         // [128][NB] (4 MB)
  float* partialPos = partialSum + (size_t)128 * NB;      // [128][NB] (4 MB)
  char* w = (char*)(partialSum + (size_t)NBLK * NPROTO * ND);
  float* protoSumG = (float*)w;     w += NPROTO * ND * 4;               // 32 KB
  int* validCnt = (int*)w;          w += 16;
  int* code = (int*)w;              w += NB * 4;
  int* validList = (int*)w;         w += NB * 4;
  float* plPart = (float*)w;        w += PL_BLOCKS * 4;
  k_norm<<<dim3(NBLK), dim3(512), 0, stream>>>(z, attr, znb, partialSum, code,
                                               protoSumG);
  k_reduce1<<<dim3(257), dim3(256), 0, stream>>>(partialSum, code, protoSumG,
                                                 validList, validCnt);
  k_main<<<dim3(PW_BLOCKS + PL_BLOCKS), dim3(512), 0, stream>>>(
      znb, protoSumG, code, validList, validCnt, partialAll, partialPos, plPart);
  k_final<<<dim3(1), dim3(1024), 0, stream>>>(partialAll, partialPos, plPart,
                                              validCnt, (float*)d_out);
}

// Round 15
// 68.454 us; speedup vs baseline: 1.0722x; 1.0526x over previous
//
#include <hip/hip_runtime.h>
#include <math.h>

#define NB 8192
#define ND 512
#define NPROTO 16
#define NBLK 256                   // k_norm grid
#define TINV 14.285714285714286f   // 1/0.07
#define PW_BLOCKS 256
#define PL_BLOCKS 256

typedef short short8 __attribute__((ext_vector_type(8)));
typedef float float4v __attribute__((ext_vector_type(4)));

__device__ __forceinline__ unsigned short f2bf(float f) {
  unsigned u = __builtin_bit_cast(unsigned, f);
  unsigned r = (u + 0x7FFFu + ((u >> 16) & 1u)) >> 16;
  return (unsigned short)r;
}
__device__ __forceinline__ float bflo(unsigned u) {
  return __builtin_bit_cast(float, u << 16);
}
__device__ __forceinline__ float bfhi(unsigned u) {
  return __builtin_bit_cast(float, u & 0xFFFF0000u);
}

// ---- K1: wave-per-row normalize + bf16 store + non-atomic partial sums ----
// d-axis stored PERMUTED: phys i=k*64+lane holds logical elem 4*lane+(k&3)+256*(k>>2).
// All consumers are dot products / norms over d -> permutation-invariant, as long
// as znb, acc, partialSum, partial2, protos share the same physical order (they do).
__global__ __launch_bounds__(512) void k_norm(
    const float* __restrict__ z, const float* __restrict__ attr,
    unsigned short* __restrict__ znb, float* __restrict__ partialSum,
    int* __restrict__ code)
{
  __shared__ float acc[NPROTO * ND];   // 32 KB
  const int t = threadIdx.x, lane = t & 63, wid = t >> 6;
  for (int i = t; i < NPROTO * ND; i += 512) acc[i] = 0.f;
  __syncthreads();
  #pragma unroll
  for (int rr = 0; rr < 4; ++rr) {
    const int r = blockIdx.x * 32 + wid * 4 + rr;
    const float4* zr4 = (const float4*)(z + (size_t)r * ND);
    const float4 va = zr4[lane];          // logical elems 4L..4L+3
    const float4 vb = zr4[lane + 64];     // logical elems 256+4L..
    float v[8] = {va.x, va.y, va.z, va.w, vb.x, vb.y, vb.z, vb.w};
    float s = 0.f;
    #pragma unroll
    for (int k = 0; k < 8; ++k) s += v[k] * v[k];
    #pragma unroll
    for (int o = 32; o > 0; o >>= 1) s += __shfl_xor(s, o);
    const float inv = 1.f / fmaxf(sqrtf(s), 1e-12f);
    const float* a = attr + (size_t)r * 4;
    const int c = (a[0] > 0.5f ? 8 : 0) | (a[1] > 0.5f ? 4 : 0) |
                  (a[2] > 0.5f ? 2 : 0) | (a[3] > 0.5f ? 1 : 0);
    float* accRow = acc + c * ND;
    #pragma unroll
    for (int k = 0; k < 8; ++k) {
      const float zv = v[k] * inv;
      atomicAdd(&accRow[k * 64 + lane], zv);         // bank=lane%32: conflict-free
      znb[(size_t)r * ND + k * 64 + lane] = f2bf(zv);
    }
    if (lane == 0) code[r] = c;
  }
  __syncthreads();
  for (int i = t; i < NPROTO * ND; i += 512) {      // full overwrite: no pre-zero
    const int p = i >> 9, d = i & 511;
    partialSum[(size_t)((p << 8) | blockIdx.x) * ND + d] = acc[i];
  }
}

// ---- K1b: stage-1 reduce: 256 blocks, (p,c) sums 16 partials --------------
__global__ __launch_bounds__(256) void k_reduce1(
    const float* __restrict__ partialSum, float* __restrict__ partial2)
{
  const int t = threadIdx.x;
  const int p = blockIdx.x >> 4, c = blockIdx.x & 15;
  const float* base = partialSum + (size_t)(p * NBLK + c * 16) * ND;
  float s0 = 0.f, s1 = 0.f;
  #pragma unroll
  for (int k = 0; k < 16; ++k) {
    s0 += base[k * ND + t];
    s1 += base[k * ND + t + 256];
  }
  partial2[(size_t)(p * 16 + c) * ND + t] = s0;
  partial2[(size_t)(p * 16 + c) * ND + t + 256] = s1;
}

// ---- K2: 16 blocks: final reduce (32KB each) + normalize + validList ------
__global__ __launch_bounds__(512) void k_protonorm(
    const float* __restrict__ partial2, const int* __restrict__ code,
    float* __restrict__ protos, int* __restrict__ validList,
    int* __restrict__ validCnt)
{
  __shared__ float red[8];
  __shared__ int lcnt;
  const int t = threadIdx.x, lane = t & 63, wid = t >> 6;
  const int p = blockIdx.x;
  if (t == 0) lcnt = 0;
  __syncthreads();
  const float* base = partial2 + (size_t)p * 16 * ND;
  float s = 0.f;
  #pragma unroll
  for (int c = 0; c < 16; ++c)
    s += base[c * ND + t];
  float cl = 0.f;
  for (int r = t; r < NB; r += 512) {
    const int match = (code[r] == p) ? 1 : 0;
    cl += (float)match;
    if (p == NPROTO - 1 && match) {
      const int slot = atomicAdd(&lcnt, 1);
      validList[slot] = r;
    }
  }
  #pragma unroll
  for (int o = 32; o > 0; o >>= 1) cl += __shfl_xor(cl, o);
  if (lane == 0) red[wid] = cl;
  __syncthreads();
  const float cTot = red[0]+red[1]+red[2]+red[3]+red[4]+red[5]+red[6]+red[7];
  __syncthreads();
  const float mean = s / fmaxf(cTot, 1.f);
  float sq = mean * mean;
  #pragma unroll
  for (int o = 32; o > 0; o >>= 1) sq += __shfl_xor(sq, o);
  if (lane == 0) red[wid] = sq;
  __syncthreads();
  const float sum = red[0]+red[1]+red[2]+red[3]+red[4]+red[5]+red[6]+red[7];
  const float scale = (cTot > 0.f) ? 1.f / fmaxf(sqrtf(sum), 1e-12f) : 0.f;
  protos[p * ND + t] = mean * scale;
  if (p == NPROTO - 1 && t == 0) validCnt[0] = lcnt;
}

// ---- K3: fused {pairwise MFMA GEMM (512thr, 64x256 tile) | protoloss} -----
#define PLD (ND + 4)
#define SMEM_BYTES 41472
__global__ __launch_bounds__(512) void k_main(
    const unsigned short* __restrict__ znb, const float* __restrict__ protos,
    const int* __restrict__ code, const int* __restrict__ validList,
    const int* __restrict__ validCnt,
    float* __restrict__ partialAll, float* __restrict__ partialPos,
    float* __restrict__ plPart)
{
  __shared__ __align__(16) char smem[SMEM_BYTES];
  __shared__ float red3[8];
  const int t = threadIdx.x, lane = t & 63, wid = t >> 6;
  const int bi = blockIdx.x;
  if (bi < PW_BLOCKS) {
    // -------- pairwise: 8 waves (2i x 4j), tile 64i x 256j, K-chunk 64 ----
    unsigned short* aT = (unsigned short*)smem;             // 64x64, 8 KB
    unsigned short* bT = aT + 64 * 64;                      // 256x64, 32 KB
    int* rowIdx = (int*)(bT + 256 * 64);                    // 64
    unsigned char* aoSh = (unsigned char*)(rowIdx + 64);    // 256
    const int wv = wid >> 2, ww = wid & 3;
    const int m = validCnt[0];
    const int nIT = (m + 63) >> 6;
    const int items = nIT * 32;                             // 32 j-tiles of 256
    const int grp = lane >> 4, cl = lane & 15;
    for (int wi = bi; wi < items; wi += PW_BLOCKS) {
      const int i0 = (wi >> 5) * 64;
      const int jt = wi & 31;
      const int jb = jt * 256;
      __syncthreads();
      if (t < 64) rowIdx[t] = (i0 + t < m) ? validList[i0 + t] : -1;
      if (t < 256) aoSh[t] = (code[jb + t] == NPROTO - 1) ? 1 : 0;
      float4v acc[2][4];
      #pragma unroll
      for (int mi = 0; mi < 2; ++mi)
        #pragma unroll
        for (int nj = 0; nj < 4; ++nj) acc[mi][nj] = (float4v)(0.f);
      for (int kc = 0; kc < 8; ++kc) {
        const int k0 = kc * 64;
        __syncthreads();
        {  // stage A: 64 rows x 8 chunks = 512, 1/thread
          const int ia = t >> 3, kq = t & 7;
          const int ri = rowIdx[ia];
          const int srow = (ri < 0) ? 0 : ri;
          const uint4 v = *(const uint4*)(znb + (size_t)srow * ND + k0 + kq * 8);
          *(uint4*)((char*)aT + ia * 128 + ((kq * 16) ^ ((ia & 7) << 4))) = v;
        }
        #pragma unroll
        for (int h = 0; h < 4; ++h) {  // stage B: 256 rows x 8 chunks, 4/thread
          const int f = t + h * 512;
          const int j = f >> 3, kq = f & 7;
          const uint4 v = *(const uint4*)(znb + (size_t)(jb + j) * ND + k0 + kq * 8);
          *(uint4*)((char*)bT + j * 128 + ((kq * 16) ^ ((j & 7) << 4))) = v;
        }
        __syncthreads();
        #pragma unroll
        for (int ks = 0; ks < 2; ++ks) {
          const int kb = ks * 64 + grp * 16;
          short8 af[2], bf[4];
          #pragma unroll
          for (int mi = 0; mi < 2; ++mi) {
            const int rw = wv * 32 + mi * 16 + cl;
            af[mi] = *(const short8*)((char*)aT + rw * 128 + (kb ^ ((rw & 7) << 4)));
          }
          #pragma unroll
          for (int nj = 0; nj < 4; ++nj) {
            const int rw = ww * 64 + nj * 16 + cl;
            bf[nj] = *(const short8*)((char*)bT + rw * 128 + (kb ^ ((rw & 7) << 4)));
          }
          #pragma unroll
          for (int mi = 0; mi < 2; ++mi)
            #pragma unroll
            for (int nj = 0; nj < 4; ++nj)
              acc[mi][nj] = __builtin_amdgcn_mfma_f32_16x16x32_bf16(af[mi], bf[nj], acc[mi][nj], 0, 0, 0);
        }
      }
      // epilogue: exp, diag+pos masks, row sums, direct partial writes
      #pragma unroll
      for (int mi = 0; mi < 2; ++mi) {
        float sA[4] = {0.f, 0.f, 0.f, 0.f}, sP[4] = {0.f, 0.f, 0.f, 0.f};
        int ri[4];
        #pragma unroll
        for (int q = 0; q < 4; ++q) ri[q] = rowIdx[wv * 32 + mi * 16 + grp * 4 + q];
        #pragma unroll
        for (int nj = 0; nj < 4; ++nj) {
          const int jl = ww * 64 + nj * 16 + cl;
          const int jg = jb + jl;
          const float ao = aoSh[jl] ? 1.f : 0.f;
          #pragma unroll
          for (int q = 0; q < 4; ++q) {
            float e = __expf(acc[mi][nj][q] * TINV);
            e = (jg == ri[q]) ? 0.f : e;
            sA[q] += e;
            sP[q] += e * ao;
          }
        }
        #pragma unroll
        for (int q = 0; q < 4; ++q) {
          #pragma unroll
          for (int o = 1; o < 16; o <<= 1) {
            sA[q] += __shfl_xor(sA[q], o);
            sP[q] += __shfl_xor(sP[q], o);
          }
        }
        if (cl == 0) {
          const int slot0 = i0 + wv * 32 + mi * 16 + grp * 4;
          const int jt2 = jt * 4 + ww;                      // 0..127
          if (slot0 + 3 < m) {
            *(float4*)&partialAll[(size_t)jt2 * NB + slot0] =
                make_float4(sA[0], sA[1], sA[2], sA[3]);
            *(float4*)&partialPos[(size_t)jt2 * NB + slot0] =
                make_float4(sP[0], sP[1], sP[2], sP[3]);
          } else {
            #pragma unroll
            for (int q = 0; q < 4; ++q) {
              if (slot0 + q < m) {
                partialAll[(size_t)jt2 * NB + slot0 + q] = sA[q];
                partialPos[(size_t)jt2 * NB + slot0 + q] = sP[q];
              }
            }
          }
        }
      }
    }
  } else {
    // -------- protoloss: 256 blocks x 512 thr, 32 rows each ---------------
    float* pl = (float*)smem;                               // [16][PLD]
    const int pb = bi - PW_BLOCKS;
    for (int i = t; i < NPROTO * ND; i += 512)
      pl[(i >> 9) * PLD + (i & 511)] = protos[i];
    __syncthreads();
    const int p = lane & 15, grp = lane >> 4;
    float lacc = 0.f;
    #pragma unroll
    for (int rr = 0; rr < 4; ++rr) {
      const int r = pb * 32 + wid * 4 + rr;
      const uint4* zr = (const uint4*)(znb + (size_t)r * ND + grp * 128);
      const float* pbp = &pl[p * PLD + grp * 128];
      float s = 0.f;
      #pragma unroll
      for (int it = 0; it < 16; ++it) {
        const uint4 u = zr[it];
        const float4 p0 = *(const float4*)(pbp + it * 8);
        const float4 p1 = *(const float4*)(pbp + it * 8 + 4);
        s += bflo(u.x)*p0.x + bfhi(u.x)*p0.y + bflo(u.y)*p0.z + bfhi(u.y)*p0.w;
        s += bflo(u.z)*p1.x + bfhi(u.z)*p1.y + bflo(u.w)*p1.z + bfhi(u.w)*p1.w;
      }
      s += __shfl_xor(s, 16);
      s += __shfl_xor(s, 32);
      const float e = __expf(s * TINV);
      float alls = e;
      alls += __shfl_xor(alls, 1);
      alls += __shfl_xor(alls, 2);
      alls += __shfl_xor(alls, 4);
      alls += __shfl_xor(alls, 8);
      const int c = code[r];
      const float pos = __shfl(e, (lane & ~15) | c);
      if (lane == 0) lacc += -logf(pos / fmaxf(alls, 1e-8f) + 1e-8f);
    }
    if (lane == 0) red3[wid] = lacc;
    __syncthreads();
    if (t == 0)
      plPart[pb] = red3[0]+red3[1]+red3[2]+red3[3]+red3[4]+red3[5]+red3[6]+red3[7];
  }
}

// ---- K4: finalize — 1024 thr, coalesced column reads, split-k halves ------
__global__ __launch_bounds__(1024) void k_final(
    const float* __restrict__ partialAll, const float* __restrict__ partialPos,
    const float* __restrict__ plPart, const int* __restrict__ validCnt,
    float* __restrict__ out)
{
  __shared__ float shA[1024], shP[1024];
  __shared__ float red[16], red2[16];
  const int t = threadIdx.x, lane = t & 63, wid = t >> 6;
  const int m = validCnt[0];
  const int nvalid = (m >= 2) ? m : 0;
  const int slot = t & 511, half = t >> 9;
  float sa = 0.f, sp = 0.f;
  if (slot < nvalid) {
    const int k0 = half * 64;
    #pragma unroll 8
    for (int k = k0; k < k0 + 64; ++k) {
      sa += partialAll[(size_t)k * NB + slot];   // coalesced across threads
      sp += partialPos[(size_t)k * NB + slot];
    }
  }
  shA[t] = sa; shP[t] = sp;
  __syncthreads();
  float s = 0.f;
  if (t < 512 && slot < nvalid) {
    const float A = shA[t] + shA[t + 512];
    const float P = shP[t] + shP[t + 512];
    s = -logf(P / (A + 1e-8f) + 1e-8f);
  }
  float pls = (t < PL_BLOCKS) ? plPart[t] : 0.f;
  #pragma unroll
  for (int o = 32; o > 0; o >>= 1) {
    s += __shfl_xor(s, o);
    pls += __shfl_xor(pls, o);
  }
  if (lane == 0) { red[wid] = s; red2[wid] = pls; }
  __syncthreads();
  if (t == 0) {
    float total = 0.f, plTot = 0.f;
    #pragma unroll
    for (int w = 0; w < 16; ++w) { total += red[w]; plTot += red2[w]; }
    const float proto = plTot / (float)NB;
    float loss = proto;
    if (nvalid > 0) loss = 0.7f * proto + 0.3f * (total / (float)nvalid);
    out[0] = loss;
  }
}

extern "C" void kernel_launch(void* const* d_in, const int* in_sizes, int n_in,
                              void* d_out, int out_size, void* d_ws, size_t ws_size,
                              hipStream_t stream) {
  const float* z = (const float*)d_in[0];
  const float* attr = (const float*)d_in[1];
  unsigned short* znb = (unsigned short*)d_ws;            // NB*ND bf16 (8 MB)
  float* partialSum = (float*)(znb + (size_t)NB * ND);    // [p][b][d] (8 MB)
  // overlay: partialSum is dead after k_reduce1/protonorm; k_main reuses it
  float* partialAll = partialSum;                         // [128][NB] (4 MB)
  float* partialPos = partialSum + (size_t)128 * NB;      // [128][NB] (4 MB)
  char* w = (char*)(partialSum + (size_t)NBLK * NPROTO * ND);
  float* partial2 = (float*)w;      w += (size_t)NPROTO * 16 * ND * 4;  // 512 KB
  int* validCnt = (int*)w;          w += 16;
  int* code = (int*)w;              w += NB * 4;
  int* validList = (int*)w;         w += NB * 4;
  float* protos = (float*)w;        w += NPROTO * ND * 4;
  float* plPart = (float*)w;        w += PL_BLOCKS * 4;
  k_norm<<<dim3(NBLK), dim3(512), 0, stream>>>(z, attr, znb, partialSum, code);
  k_reduce1<<<dim3(256), dim3(256), 0, stream>>>(partialSum, partial2);
  k_protonorm<<<dim3(NPROTO), dim3(512), 0, stream>>>(partial2, code, protos,
                                                      validList, validCnt);
  k_main<<<dim3(PW_BLOCKS + PL_BLOCKS), dim3(512), 0, stream>>>(
      znb, protos, code, validList, validCnt, partialAll, partialPos, plPart);
  k_final<<<dim3(1), dim3(1024), 0, stream>>>(partialAll, partialPos, plPart,
                                              validCnt, (float*)d_out);
}